// Round 4
// baseline (115.972 us; speedup 1.0000x reference)
//
#include <hip/hip_runtime.h>
#include <hip/hip_bf16.h>

#define BATCH 4
#define NB    256
#define NE    (NB*(NB-1))   // 65280

typedef short    short8 __attribute__((ext_vector_type(8)));
typedef float    f32x16 __attribute__((ext_vector_type(16)));
typedef unsigned u32x4  __attribute__((ext_vector_type(4)));

__device__ __forceinline__ short f2bf(float x) {
    return __builtin_bit_cast(short, __float2bfloat16(x));   // RNE
}
__device__ __forceinline__ unsigned pk2(float lo, float hi) {
    return (unsigned)(unsigned short)f2bf(lo) |
           ((unsigned)(unsigned short)f2bf(hi) << 16);
}
// v_permlane32_swap_b32: a.upper32lanes <-> b.lower32lanes
__device__ __forceinline__ void pl32swap(unsigned& a, unsigned& b) {
    asm volatile("v_permlane32_swap_b32 %0, %1" : "+v"(a), "+v"(b));
}

// A1 fragments for swapped GEMM1: lane holds W1[i][f=16k0+8lh+j][h=l31+32ht]
__device__ __forceinline__ void loadA1(const float* __restrict__ W1i,
                                       int l31, int lh, short8 a1f[2][4]) {
    #pragma unroll
    for (int ht = 0; ht < 2; ++ht)
        #pragma unroll
        for (int k0 = 0; k0 < 4; ++k0) {
            const int h  = l31 + 32 * ht;
            const int fb = 16 * k0 + 8 * lh;
            short8 v;
            #pragma unroll
            for (int j = 0; j < 8; ++j) v[j] = f2bf(W1i[(fb + j) * 64 + h]);
            a1f[ht][k0] = v;
        }
}

// ---------------------------------------------------------------------------
// Single fused kernel: one wg per (b, receiver r); 256 threads = 4 waves.
// B1 fragments gathered DIRECTLY from global x (L2-resident) — no x LDS tile.
// Tiles (i, et) fully serialized to keep peak VGPR ~135 (R3 spilled at ~160).
// ---------------------------------------------------------------------------
__global__ __launch_bounds__(256, 3) void fused_kernel(
    const float* __restrict__ x,        // [B][N][64]
    const float* __restrict__ rel_type, // [B][E][2]
    const float* __restrict__ W1,       // [2][128][64]
    const float* __restrict__ b1,       // [2][64]
    const float* __restrict__ W2,       // [2][64][64]
    const float* __restrict__ b2,       // [2][64]
    const float* __restrict__ Wo1,      // [128][64]
    const float* __restrict__ bo1,      // [64]
    const float* __restrict__ Wo2,      // [64][64]
    const float* __restrict__ bo2,      // [64]
    float* __restrict__ out)
{
    const int b    = blockIdx.x >> 8;
    const int r    = blockIdx.x & 255;
    const int t    = threadIdx.x;
    const int lane = t & 63;
    const int w    = t >> 6;
    const int l31  = lane & 31;
    const int lh   = lane >> 5;

    __shared__ __align__(16) short W2l[8192];      // 16 KiB B-fragments
    __shared__ __align__(16) float rt2[2][256];    // 2 KiB
    __shared__ __align__(16) float qrow[2][64];
    __shared__ __align__(16) float red[4][64];
    __shared__ __align__(16) float xl[64];
    __shared__ __align__(16) float aggl[64];
    __shared__ __align__(16) float predl[64];

    const float* xb = x + (size_t)b * (NB * 64);

    // ---- phase A: rt + xl staging, b1f direct-global gather, a1f type-0 ----
    if (t < 255) {
        const float* p = rel_type + ((size_t)b * NE + (size_t)r * 255 + t) * 2;
        rt2[0][t] = p[0];
        rt2[1][t] = p[1];
    } else {
        rt2[0][255] = 0.f; rt2[1][255] = 0.f;      // pad edge contributes 0
    }
    if (t >= 192) xl[t - 192] = xb[r * 64 + (t - 192)];

    short8 b1f[2][4];
    #pragma unroll
    for (int et = 0; et < 2; ++et) {
        const int kap = 64 * w + 32 * et + l31;
        int s = (kap < r) ? kap : kap + 1;
        if (s > 255) s = 255;                       // pad row, rt=0
        const float* row = xb + s * 64;
        #pragma unroll
        for (int k0 = 0; k0 < 4; ++k0) {
            float4 u0 = *(const float4*)(row + 16 * k0 + 8 * lh);
            float4 u1 = *(const float4*)(row + 16 * k0 + 8 * lh + 4);
            short8 v = { f2bf(u0.x), f2bf(u0.y), f2bf(u0.z), f2bf(u0.w),
                         f2bf(u1.x), f2bf(u1.y), f2bf(u1.z), f2bf(u1.w) };
            b1f[et][k0] = v;
        }
    }

    short8 a1f[2][4];
    loadA1(W1, l31, lh, a1f);

    const float bv00 = b2[l31],      bv01 = b2[32 + l31];
    const float bv10 = b2[64 + l31], bv11 = b2[96 + l31];

    __syncthreads();   // xl ready

    // ---- phase B: q-row (waves 0-1) | W2 fragment staging (waves 2-3) ----
    if (t < 128) {
        const int i = t >> 6, h = t & 63;
        float acc = b1[i * 64 + h];
        const float* w1r = W1 + i * 8192 + 4096;   // receiver rows 64..127
        #pragma unroll 16
        for (int f = 0; f < 64; ++f) acc = fmaf(xl[f], w1r[f * 64 + h], acc);
        qrow[i][h] = acc;
    } else {
        const int i  = (t >> 6) - 2;
        const int ln = t & 63;
        #pragma unroll
        for (int c = 0; c < 8; ++c) {              // c = nh*4 + k0
            const int nh = c >> 2, k0 = c & 3;
            short8 v;
            #pragma unroll
            for (int j = 0; j < 8; ++j) {
                const int k = 16 * k0 + 8 * (ln >> 5) + j;
                const int n = (ln & 31) + 32 * nh;
                v[j] = f2bf(W2[(i * 64 + k) * 64 + n]);
            }
            *(short8*)(W2l + ((i * 8 + c) * 64 + ln) * 8) = v;
        }
    }
    __syncthreads();

    float psum0 = 0.f, psum1 = 0.f;   // per-lane agg partials, h = l31 / l31+32

    #pragma unroll
    for (int i = 0; i < 2; ++i) {
        #pragma unroll
        for (int et = 0; et < 2; ++et) {
            // ---- GEMM1 (swapped): acc1[ht] = q + W1T @ xsT ----
            f32x16 acc1[2];
            #pragma unroll
            for (int ht = 0; ht < 2; ++ht) {
                f32x16 a;
                #pragma unroll
                for (int qd = 0; qd < 4; ++qd) {
                    float4 qq = *(const float4*)(&qrow[i][32 * ht + 8 * qd + 4 * lh]);
                    a[4 * qd] = qq.x; a[4 * qd + 1] = qq.y;
                    a[4 * qd + 2] = qq.z; a[4 * qd + 3] = qq.w;
                }
                #pragma unroll
                for (int k0 = 0; k0 < 4; ++k0)
                    a = __builtin_amdgcn_mfma_f32_32x32x16_bf16(a1f[ht][k0],
                                                                b1f[et][k0], a, 0, 0, 0);
                acc1[ht] = a;
            }

            // ---- relu + repack (h-in-regs -> k-elems of A2) ----
            short8 a2f[4];
            #pragma unroll
            for (int k0 = 0; k0 < 4; ++k0) {
                const int ht = k0 >> 1;
                const int qa = 2 * (k0 & 1), qb = qa + 1;
                unsigned a0 = pk2(fmaxf(acc1[ht][4 * qa], 0.f),
                                  fmaxf(acc1[ht][4 * qa + 1], 0.f));
                unsigned a1 = pk2(fmaxf(acc1[ht][4 * qa + 2], 0.f),
                                  fmaxf(acc1[ht][4 * qa + 3], 0.f));
                unsigned b0 = pk2(fmaxf(acc1[ht][4 * qb], 0.f),
                                  fmaxf(acc1[ht][4 * qb + 1], 0.f));
                unsigned b1w = pk2(fmaxf(acc1[ht][4 * qb + 2], 0.f),
                                   fmaxf(acc1[ht][4 * qb + 3], 0.f));
                pl32swap(a0, b0);
                pl32swap(a1, b1w);
                u32x4 fw = { a0, a1, b0, b1w };
                a2f[k0] = __builtin_bit_cast(short8, fw);
            }

            // prefetch type-1 W1 frags in the (0,1)-tile shadow (acc1 dead here)
            if (i == 0 && et == 1) loadA1(W1 + 8192, l31, lh, a1f);

            // ---- GEMM2: msg1 @ W2 (+b2 in C-init) ----
            f32x16 acc20, acc21;
            const float bvA = (i == 0) ? bv00 : bv10;
            const float bvB = (i == 0) ? bv01 : bv11;
            #pragma unroll
            for (int e = 0; e < 16; ++e) { acc20[e] = bvA; acc21[e] = bvB; }
            #pragma unroll
            for (int k0 = 0; k0 < 4; ++k0) {
                const short8 B0 = *(const short8*)(W2l + ((i * 8 + k0) * 64 + lane) * 8);
                const short8 B1 = *(const short8*)(W2l + ((i * 8 + 4 + k0) * 64 + lane) * 8);
                acc20 = __builtin_amdgcn_mfma_f32_32x32x16_bf16(a2f[k0], B0, acc20, 0, 0, 0);
                acc21 = __builtin_amdgcn_mfma_f32_32x32x16_bf16(a2f[k0], B1, acc21, 0, 0, 0);
            }

            // ---- bias/relu done, weight by rel_type, row-reduce ----
            #pragma unroll
            for (int qd = 0; qd < 4; ++qd) {
                float4 rq = *(const float4*)(&rt2[i][64 * w + 32 * et + 8 * qd + 4 * lh]);
                #pragma unroll
                for (int m = 0; m < 4; ++m) {
                    psum0 += fmaxf(acc20[4 * qd + m], 0.f) * rq[m];
                    psum1 += fmaxf(acc21[4 * qd + m], 0.f) * rq[m];
                }
            }
        }
    }

    // prefetch output-MLP layer-1 weights (latency hides under reductions)
    float wv1[32];
    #pragma unroll
    for (int jj = 0; jj < 32; ++jj) wv1[jj] = Wo1[(w * 32 + jj) * 64 + lane];

    // ---- reduce: lane-halves, then waves ----
    psum0 += __shfl_xor(psum0, 32, 64);
    psum1 += __shfl_xor(psum1, 32, 64);
    if (lh == 0) {
        red[w][l31]      = psum0;
        red[w][l31 + 32] = psum1;
    }
    __syncthreads();
    if (t < 64) aggl[t] = red[0][t] + red[1][t] + red[2][t] + red[3][t];
    __syncthreads();

    // ---- output MLP layer 1: aug(128) @ Wo1(128x64) ----
    {
        const float* src = (w < 2) ? (xl + w * 32) : (aggl + (w - 2) * 32);
        float s = 0.f;
        #pragma unroll
        for (int jj = 0; jj < 32; ++jj) s = fmaf(src[jj], wv1[jj], s);
        red[w][lane] = s;
    }
    __syncthreads();
    if (t < 64)
        predl[t] = fmaxf(red[0][t] + red[1][t] + red[2][t] + red[3][t] + bo1[t], 0.f);
    __syncthreads();

    // ---- output MLP layer 2 + residual ----
    {
        const float* Wp = Wo2 + (w * 16) * 64 + lane;
        float s = 0.f;
        #pragma unroll
        for (int jj = 0; jj < 16; ++jj) s = fmaf(predl[w * 16 + jj], Wp[jj * 64], s);
        red[w][lane] = s;
    }
    __syncthreads();
    if (t < 64)
        out[((size_t)b * NB + r) * 64 + t] =
            xl[t] + fmaxf(red[0][t] + red[1][t] + red[2][t] + red[3][t] + bo2[t], 0.f);
}

// ---------------------------------------------------------------------------
extern "C" void kernel_launch(void* const* d_in, const int* in_sizes, int n_in,
                              void* d_out, int out_size, void* d_ws, size_t ws_size,
                              hipStream_t stream) {
    (void)in_sizes; (void)n_in; (void)out_size; (void)d_ws; (void)ws_size;

    const float* x    = (const float*)d_in[0];
    const float* rt   = (const float*)d_in[1];
    // d_in[2] = rel_rec, d_in[3] = rel_send: dense all-pairs one-hot, unused
    const float* W1   = (const float*)d_in[4];
    const float* b1   = (const float*)d_in[5];
    const float* W2   = (const float*)d_in[6];
    const float* b2   = (const float*)d_in[7];
    const float* Wo1  = (const float*)d_in[8];
    const float* bo1  = (const float*)d_in[9];
    const float* Wo2  = (const float*)d_in[10];
    const float* bo2  = (const float*)d_in[11];
    float* out = (float*)d_out;

    fused_kernel<<<BATCH * NB, 256, 0, stream>>>(x, rt, W1, b1, W2, b2,
                                                 Wo1, bo1, Wo2, bo2, out);
}

// Round 5
// 59.692 us; speedup vs baseline: 1.9428x; 1.9428x over previous
//
#include <hip/hip_runtime.h>
#include <hip/hip_bf16.h>

#define BATCH 4
#define NB    256
#define NE    (NB*(NB-1))   // 65280

typedef short    short8 __attribute__((ext_vector_type(8)));
typedef float    f32x16 __attribute__((ext_vector_type(16)));
typedef unsigned u32x4  __attribute__((ext_vector_type(4)));

static __device__ __forceinline__ short f2bf(float x) {
    return __builtin_bit_cast(short, __float2bfloat16(x));   // RNE
}
static __device__ __forceinline__ unsigned pk2(float lo, float hi) {
    return (unsigned)(unsigned short)f2bf(lo) |
           ((unsigned)(unsigned short)f2bf(hi) << 16);
}
// v_permlane32_swap_b32: a.upper32lanes <-> b.lower32lanes
static __device__ __forceinline__ void pl32swap(unsigned& a, unsigned& b) {
    asm volatile("v_permlane32_swap_b32 %0, %1" : "+v"(a), "+v"(b));
}
static __device__ __forceinline__ f32x16 splat16(float v) {
    f32x16 r;
    #pragma unroll
    for (int e = 0; e < 16; ++e) r[e] = v;
    return r;
}

// ---- fragment builders: named-var only, no arrays anywhere ----------------
// A1 frag (swapped GEMM1 A-op): lane holds W1[f = 16*K0+8*lh + j][h = l31+32*HT]
#define MK_A1(dst, Wp, K0, HT) do {                                            \
    const float* _p = (Wp) + (16*(K0) + 8*lh) * 64 + (l31 + 32*(HT));          \
    short8 _v;                                                                 \
    _v[0]=f2bf(_p[0]);   _v[1]=f2bf(_p[64]);  _v[2]=f2bf(_p[128]);             \
    _v[3]=f2bf(_p[192]); _v[4]=f2bf(_p[256]); _v[5]=f2bf(_p[320]);             \
    _v[6]=f2bf(_p[384]); _v[7]=f2bf(_p[448]);                                  \
    (dst) = _v; } while (0)

// B1 frag: sender-row slice x[s][16*K0+8*lh .. +8]
#define MK_B1(dst, ROW, K0) do {                                               \
    float4 _u0 = *(const float4*)((ROW) + 16*(K0) + 8*lh);                     \
    float4 _u1 = *(const float4*)((ROW) + 16*(K0) + 8*lh + 4);                 \
    short8 _v = { f2bf(_u0.x), f2bf(_u0.y), f2bf(_u0.z), f2bf(_u0.w),          \
                  f2bf(_u1.x), f2bf(_u1.y), f2bf(_u1.z), f2bf(_u1.w) };        \
    (dst) = _v; } while (0)

// GEMM1 C-init from qrow (C[4qd+m] = qrow[32*HT + 8*qd + 4*lh + m])
#define G1_INIT(C, QP, HT) do {                                                \
    float4 _q0 = *(const float4*)((QP) + 32*(HT) + 4*lh);                      \
    float4 _q1 = *(const float4*)((QP) + 32*(HT) + 8 + 4*lh);                  \
    float4 _q2 = *(const float4*)((QP) + 32*(HT) + 16 + 4*lh);                 \
    float4 _q3 = *(const float4*)((QP) + 32*(HT) + 24 + 4*lh);                 \
    (C)[0]=_q0.x;(C)[1]=_q0.y;(C)[2]=_q0.z;(C)[3]=_q0.w;                       \
    (C)[4]=_q1.x;(C)[5]=_q1.y;(C)[6]=_q1.z;(C)[7]=_q1.w;                       \
    (C)[8]=_q2.x;(C)[9]=_q2.y;(C)[10]=_q2.z;(C)[11]=_q2.w;                     \
    (C)[12]=_q3.x;(C)[13]=_q3.y;(C)[14]=_q3.z;(C)[15]=_q3.w; } while (0)

// relu + cvt_pk + permlane32_swap repack of two acc1 quads -> one A2 fragment
#define REPACK(dst, C, QA, QB) do {                                            \
    unsigned _a0 = pk2(fmaxf((C)[4*(QA)],   0.f), fmaxf((C)[4*(QA)+1], 0.f));  \
    unsigned _a1 = pk2(fmaxf((C)[4*(QA)+2], 0.f), fmaxf((C)[4*(QA)+3], 0.f));  \
    unsigned _b0 = pk2(fmaxf((C)[4*(QB)],   0.f), fmaxf((C)[4*(QB)+1], 0.f));  \
    unsigned _b1 = pk2(fmaxf((C)[4*(QB)+2], 0.f), fmaxf((C)[4*(QB)+3], 0.f));  \
    pl32swap(_a0, _b0); pl32swap(_a1, _b1);                                    \
    u32x4 _fw = { _a0, _a1, _b0, _b1 };                                        \
    (dst) = __builtin_bit_cast(short8, _fw); } while (0)

#define MFMA(C, A, B) C = __builtin_amdgcn_mfma_f32_32x32x16_bf16(A, B, C, 0, 0, 0)

// epilogue quad: weight 4 acc elements by rel_type and add into psums
#define EPI_QD(C2A, C2B, I, ET, QD) do {                                       \
    float4 _rq = *(const float4*)(&rt2[I][64*w + 32*(ET) + 8*(QD) + 4*lh]);    \
    psum0 += fmaxf((C2A)[4*(QD)],   0.f) * _rq.x;                              \
    psum0 += fmaxf((C2A)[4*(QD)+1], 0.f) * _rq.y;                              \
    psum0 += fmaxf((C2A)[4*(QD)+2], 0.f) * _rq.z;                              \
    psum0 += fmaxf((C2A)[4*(QD)+3], 0.f) * _rq.w;                              \
    psum1 += fmaxf((C2B)[4*(QD)],   0.f) * _rq.x;                              \
    psum1 += fmaxf((C2B)[4*(QD)+1], 0.f) * _rq.y;                              \
    psum1 += fmaxf((C2B)[4*(QD)+2], 0.f) * _rq.z;                              \
    psum1 += fmaxf((C2B)[4*(QD)+3], 0.f) * _rq.w; } while (0)

// one (edge-type I, edge-tile ET) macro-tile: GEMM1 -> repack -> GEMM2 -> epi
#define TILE(I, ET, BF0, BF1, BF2, BF3, BVA, BVB) do {                         \
    f32x16 _c1a, _c1b;                                                         \
    G1_INIT(_c1a, &qrow[I][0], 0);                                             \
    G1_INIT(_c1b, &qrow[I][0], 1);                                             \
    MFMA(_c1a, A1L0, BF0); MFMA(_c1a, A1L1, BF1);                              \
    MFMA(_c1a, A1L2, BF2); MFMA(_c1a, A1L3, BF3);                              \
    MFMA(_c1b, A1H0, BF0); MFMA(_c1b, A1H1, BF1);                              \
    MFMA(_c1b, A1H2, BF2); MFMA(_c1b, A1H3, BF3);                              \
    short8 _a20, _a21, _a22, _a23;                                             \
    REPACK(_a20, _c1a, 0, 1); REPACK(_a21, _c1a, 2, 3);                        \
    REPACK(_a22, _c1b, 0, 1); REPACK(_a23, _c1b, 2, 3);                        \
    f32x16 _c2a = splat16(BVA), _c2b = splat16(BVB);                           \
    short8 _w20 = *(const short8*)(W2l + (((I)*8 + 0)*64 + lane)*8);           \
    short8 _w24 = *(const short8*)(W2l + (((I)*8 + 4)*64 + lane)*8);           \
    MFMA(_c2a, _a20, _w20); MFMA(_c2b, _a20, _w24);                            \
    short8 _w21 = *(const short8*)(W2l + (((I)*8 + 1)*64 + lane)*8);           \
    short8 _w25 = *(const short8*)(W2l + (((I)*8 + 5)*64 + lane)*8);           \
    MFMA(_c2a, _a21, _w21); MFMA(_c2b, _a21, _w25);                            \
    short8 _w22 = *(const short8*)(W2l + (((I)*8 + 2)*64 + lane)*8);           \
    short8 _w26 = *(const short8*)(W2l + (((I)*8 + 6)*64 + lane)*8);           \
    MFMA(_c2a, _a22, _w22); MFMA(_c2b, _a22, _w26);                            \
    short8 _w23 = *(const short8*)(W2l + (((I)*8 + 3)*64 + lane)*8);           \
    short8 _w27 = *(const short8*)(W2l + (((I)*8 + 7)*64 + lane)*8);           \
    MFMA(_c2a, _a23, _w23); MFMA(_c2b, _a23, _w27);                            \
    EPI_QD(_c2a, _c2b, I, ET, 0); EPI_QD(_c2a, _c2b, I, ET, 1);                \
    EPI_QD(_c2a, _c2b, I, ET, 2); EPI_QD(_c2a, _c2b, I, ET, 3); } while (0)

// ---------------------------------------------------------------------------
// Single fused kernel: one wg per (b, receiver r); 256 threads = 4 waves.
// Fully scalarized: no local arrays (R4's scratch-spill pathology).
// ---------------------------------------------------------------------------
__global__ __launch_bounds__(256) void fused_kernel(
    const float* __restrict__ x,        // [B][N][64]
    const float* __restrict__ rel_type, // [B][E][2]
    const float* __restrict__ W1,       // [2][128][64]
    const float* __restrict__ b1,       // [2][64]
    const float* __restrict__ W2,       // [2][64][64]
    const float* __restrict__ b2,       // [2][64]
    const float* __restrict__ Wo1,      // [128][64]
    const float* __restrict__ bo1,      // [64]
    const float* __restrict__ Wo2,      // [64][64]
    const float* __restrict__ bo2,      // [64]
    float* __restrict__ out)
{
    const int b    = blockIdx.x >> 8;
    const int r    = blockIdx.x & 255;
    const int t    = threadIdx.x;
    const int lane = t & 63;
    const int w    = t >> 6;
    const int l31  = lane & 31;
    const int lh   = lane >> 5;

    __shared__ __align__(16) short W2l[8192];      // 16 KiB B-fragments
    __shared__ __align__(16) float rt2[2][256];    // 2 KiB
    __shared__ __align__(16) float qrow[2][64];
    __shared__ __align__(16) float red[4][64];
    __shared__ __align__(16) float xl[64];
    __shared__ __align__(16) float aggl[64];
    __shared__ __align__(16) float predl[64];

    const float* xb = x + (size_t)b * (NB * 64);

    // ---- phase A: rt + xl staging, B1 gathers, A1 type-0 fragments ----
    if (t < 255) {
        const float* p = rel_type + ((size_t)b * NE + (size_t)r * 255 + t) * 2;
        rt2[0][t] = p[0];
        rt2[1][t] = p[1];
    } else {
        rt2[0][255] = 0.f; rt2[1][255] = 0.f;      // pad edge contributes 0
    }
    if (t >= 192) xl[t - 192] = xb[r * 64 + (t - 192)];

    const int kap0 = 64 * w + l31;
    const int kap1 = kap0 + 32;
    int s0 = (kap0 < r) ? kap0 : kap0 + 1; if (s0 > 255) s0 = 255;  // pad row
    int s1 = (kap1 < r) ? kap1 : kap1 + 1; if (s1 > 255) s1 = 255;
    const float* rowA = xb + s0 * 64;
    const float* rowB = xb + s1 * 64;

    short8 B1A0, B1A1, B1A2, B1A3, B1B0, B1B1, B1B2, B1B3;
    MK_B1(B1A0, rowA, 0); MK_B1(B1A1, rowA, 1);
    MK_B1(B1A2, rowA, 2); MK_B1(B1A3, rowA, 3);
    MK_B1(B1B0, rowB, 0); MK_B1(B1B1, rowB, 1);
    MK_B1(B1B2, rowB, 2); MK_B1(B1B3, rowB, 3);

    short8 A1L0, A1L1, A1L2, A1L3, A1H0, A1H1, A1H2, A1H3;
    MK_A1(A1L0, W1, 0, 0); MK_A1(A1L1, W1, 1, 0);
    MK_A1(A1L2, W1, 2, 0); MK_A1(A1L3, W1, 3, 0);
    MK_A1(A1H0, W1, 0, 1); MK_A1(A1H1, W1, 1, 1);
    MK_A1(A1H2, W1, 2, 1); MK_A1(A1H3, W1, 3, 1);

    const float bv00 = b2[l31],      bv01 = b2[32 + l31];
    const float bv10 = b2[64 + l31], bv11 = b2[96 + l31];

    __syncthreads();   // xl ready

    // ---- phase B: q-row (waves 0-1) | W2 fragment staging (waves 2-3) ----
    if (t < 128) {
        const int i = t >> 6, h = t & 63;
        float acc = b1[i * 64 + h];
        const float* w1r = W1 + i * 8192 + 4096;   // receiver rows 64..127
        #pragma unroll 16
        for (int f = 0; f < 64; ++f) acc = fmaf(xl[f], w1r[f * 64 + h], acc);
        qrow[i][h] = acc;
    } else {
        const int i  = (t >> 6) - 2;
        const int ln = t & 63;
        #pragma unroll
        for (int c = 0; c < 8; ++c) {              // c = nh*4 + k0
            const int nh = c >> 2, k0 = c & 3;
            short8 v;
            #pragma unroll
            for (int j = 0; j < 8; ++j) {
                const int k = 16 * k0 + 8 * (ln >> 5) + j;
                const int n = (ln & 31) + 32 * nh;
                v[j] = f2bf(W2[(i * 64 + k) * 64 + n]);
            }
            *(short8*)(W2l + ((i * 8 + c) * 64 + ln) * 8) = v;
        }
    }
    __syncthreads();

    float psum0 = 0.f, psum1 = 0.f;   // per-lane agg partials, h = l31 / l31+32

    // ---- type 0, both edge tiles ----
    TILE(0, 0, B1A0, B1A1, B1A2, B1A3, bv00, bv01);
    TILE(0, 1, B1B0, B1B1, B1B2, B1B3, bv00, bv01);

    // reload A1 fragments for type 1
    {
        const float* W1b = W1 + 8192;
        MK_A1(A1L0, W1b, 0, 0); MK_A1(A1L1, W1b, 1, 0);
        MK_A1(A1L2, W1b, 2, 0); MK_A1(A1L3, W1b, 3, 0);
        MK_A1(A1H0, W1b, 0, 1); MK_A1(A1H1, W1b, 1, 1);
        MK_A1(A1H2, W1b, 2, 1); MK_A1(A1H3, W1b, 3, 1);
    }

    // ---- type 1, both edge tiles ----
    TILE(1, 0, B1A0, B1A1, B1A2, B1A3, bv10, bv11);
    TILE(1, 1, B1B0, B1B1, B1B2, B1B3, bv10, bv11);

    // ---- reduce: lane-halves, then waves ----
    psum0 += __shfl_xor(psum0, 32, 64);
    psum1 += __shfl_xor(psum1, 32, 64);
    if (lh == 0) {
        red[w][l31]      = psum0;
        red[w][l31 + 32] = psum1;
    }
    __syncthreads();
    if (t < 64) aggl[t] = red[0][t] + red[1][t] + red[2][t] + red[3][t];
    __syncthreads();

    // ---- output MLP layer 1: aug(128) @ Wo1(128x64) ----
    {
        const float* src = (w < 2) ? (xl + w * 32) : (aggl + (w - 2) * 32);
        const float* Wp  = Wo1 + (w * 32) * 64 + lane;
        float s = 0.f;
        #pragma unroll
        for (int jj = 0; jj < 32; ++jj) s = fmaf(src[jj], Wp[jj * 64], s);
        red[w][lane] = s;
    }
    __syncthreads();
    if (t < 64)
        predl[t] = fmaxf(red[0][t] + red[1][t] + red[2][t] + red[3][t] + bo1[t], 0.f);
    __syncthreads();

    // ---- output MLP layer 2 + residual ----
    {
        const float* Wp = Wo2 + (w * 16) * 64 + lane;
        float s = 0.f;
        #pragma unroll
        for (int jj = 0; jj < 16; ++jj) s = fmaf(predl[w * 16 + jj], Wp[jj * 64], s);
        red[w][lane] = s;
    }
    __syncthreads();
    if (t < 64)
        out[((size_t)b * NB + r) * 64 + t] =
            xl[t] + fmaxf(red[0][t] + red[1][t] + red[2][t] + red[3][t] + bo2[t], 0.f);
}

// ---------------------------------------------------------------------------
extern "C" void kernel_launch(void* const* d_in, const int* in_sizes, int n_in,
                              void* d_out, int out_size, void* d_ws, size_t ws_size,
                              hipStream_t stream) {
    (void)in_sizes; (void)n_in; (void)out_size; (void)d_ws; (void)ws_size;

    const float* x    = (const float*)d_in[0];
    const float* rt   = (const float*)d_in[1];
    // d_in[2] = rel_rec, d_in[3] = rel_send: dense all-pairs one-hot, unused
    const float* W1   = (const float*)d_in[4];
    const float* b1   = (const float*)d_in[5];
    const float* W2   = (const float*)d_in[6];
    const float* b2   = (const float*)d_in[7];
    const float* Wo1  = (const float*)d_in[8];
    const float* bo1  = (const float*)d_in[9];
    const float* Wo2  = (const float*)d_in[10];
    const float* bo2  = (const float*)d_in[11];
    float* out = (float*)d_out;

    fused_kernel<<<BATCH * NB, 256, 0, stream>>>(x, rt, W1, b1, W2, b2,
                                                 Wo1, bo1, Wo2, bo2, out);
}

// Round 6
// 30.715 us; speedup vs baseline: 3.7758x; 1.9434x over previous
//
#include <hip/hip_runtime.h>
#include <hip/hip_bf16.h>

#define BATCH 4
#define NB    256
#define NE    (NB*(NB-1))   // 65280

typedef short    short8 __attribute__((ext_vector_type(8)));
typedef float    f32x16 __attribute__((ext_vector_type(16)));
typedef unsigned u32x4  __attribute__((ext_vector_type(4)));

static __device__ __forceinline__ short f2bf(float x) {
    return __builtin_bit_cast(short, __float2bfloat16(x));   // RNE
}
static __device__ __forceinline__ unsigned pk2(float lo, float hi) {
    return (unsigned)(unsigned short)f2bf(lo) |
           ((unsigned)(unsigned short)f2bf(hi) << 16);
}
// v_permlane32_swap_b32: a.upper32lanes <-> b.lower32lanes
static __device__ __forceinline__ void pl32swap(unsigned& a, unsigned& b) {
    asm volatile("v_permlane32_swap_b32 %0, %1" : "+v"(a), "+v"(b));
}
static __device__ __forceinline__ f32x16 splat16(float v) {
    f32x16 r;
    #pragma unroll
    for (int e = 0; e < 16; ++e) r[e] = v;
    return r;
}

// B1 frag: sender-row slice x[s][16*K0+8*lh .. +8]
#define MK_B1(dst, ROW, K0) do {                                               \
    float4 _u0 = *(const float4*)((ROW) + 16*(K0) + 8*lh);                     \
    float4 _u1 = *(const float4*)((ROW) + 16*(K0) + 8*lh + 4);                 \
    short8 _v = { f2bf(_u0.x), f2bf(_u0.y), f2bf(_u0.z), f2bf(_u0.w),          \
                  f2bf(_u1.x), f2bf(_u1.y), f2bf(_u1.z), f2bf(_u1.w) };        \
    (dst) = _v; } while (0)

// GEMM1 C-init from qrow (C[4qd+m] = qrow[32*HT + 8*qd + 4*lh + m])
#define G1_INIT(C, QP, HT) do {                                                \
    float4 _q0 = *(const float4*)((QP) + 32*(HT) + 4*lh);                      \
    float4 _q1 = *(const float4*)((QP) + 32*(HT) + 8 + 4*lh);                  \
    float4 _q2 = *(const float4*)((QP) + 32*(HT) + 16 + 4*lh);                 \
    float4 _q3 = *(const float4*)((QP) + 32*(HT) + 24 + 4*lh);                 \
    (C)[0]=_q0.x;(C)[1]=_q0.y;(C)[2]=_q0.z;(C)[3]=_q0.w;                       \
    (C)[4]=_q1.x;(C)[5]=_q1.y;(C)[6]=_q1.z;(C)[7]=_q1.w;                       \
    (C)[8]=_q2.x;(C)[9]=_q2.y;(C)[10]=_q2.z;(C)[11]=_q2.w;                     \
    (C)[12]=_q3.x;(C)[13]=_q3.y;(C)[14]=_q3.z;(C)[15]=_q3.w; } while (0)

// relu + cvt_pk + permlane32_swap repack of two acc1 quads -> one A2 fragment
#define REPACK(dst, C, QA, QB) do {                                            \
    unsigned _a0 = pk2(fmaxf((C)[4*(QA)],   0.f), fmaxf((C)[4*(QA)+1], 0.f));  \
    unsigned _a1 = pk2(fmaxf((C)[4*(QA)+2], 0.f), fmaxf((C)[4*(QA)+3], 0.f));  \
    unsigned _b0 = pk2(fmaxf((C)[4*(QB)],   0.f), fmaxf((C)[4*(QB)+1], 0.f));  \
    unsigned _b1 = pk2(fmaxf((C)[4*(QB)+2], 0.f), fmaxf((C)[4*(QB)+3], 0.f));  \
    pl32swap(_a0, _b0); pl32swap(_a1, _b1);                                    \
    u32x4 _fw = { _a0, _a1, _b0, _b1 };                                        \
    (dst) = __builtin_bit_cast(short8, _fw); } while (0)

#define MFMA(C, A, B) C = __builtin_amdgcn_mfma_f32_32x32x16_bf16(A, B, C, 0, 0, 0)

// epilogue quad: weight 4 acc elements by rel_type and add into psums
#define EPI_QD(C2A, C2B, I, ET, QD) do {                                       \
    float4 _rq = *(const float4*)(&rt2[I][64*w + 32*(ET) + 8*(QD) + 4*lh]);    \
    psum0 += fmaxf((C2A)[4*(QD)],   0.f) * _rq.x;                              \
    psum0 += fmaxf((C2A)[4*(QD)+1], 0.f) * _rq.y;                              \
    psum0 += fmaxf((C2A)[4*(QD)+2], 0.f) * _rq.z;                              \
    psum0 += fmaxf((C2A)[4*(QD)+3], 0.f) * _rq.w;                              \
    psum1 += fmaxf((C2B)[4*(QD)],   0.f) * _rq.x;                              \
    psum1 += fmaxf((C2B)[4*(QD)+1], 0.f) * _rq.y;                              \
    psum1 += fmaxf((C2B)[4*(QD)+2], 0.f) * _rq.z;                              \
    psum1 += fmaxf((C2B)[4*(QD)+3], 0.f) * _rq.w; } while (0)

// one (edge-type I, edge-tile ET) macro-tile: GEMM1 -> repack -> GEMM2 -> epi
// A1 fragments come from LDS (W1f) via conflict-free lane-consecutive b128 reads.
#define TILE(I, ET, BF0, BF1, BF2, BF3, BVA, BVB) do {                         \
    f32x16 _c1a, _c1b;                                                         \
    G1_INIT(_c1a, &qrow[I][0], 0);                                             \
    G1_INIT(_c1b, &qrow[I][0], 1);                                             \
    {                                                                          \
        short8 _f0 = *(const short8*)(W1f + (((I)*8+0)*64 + lane)*8);          \
        short8 _f1 = *(const short8*)(W1f + (((I)*8+1)*64 + lane)*8);          \
        short8 _f2 = *(const short8*)(W1f + (((I)*8+2)*64 + lane)*8);          \
        short8 _f3 = *(const short8*)(W1f + (((I)*8+3)*64 + lane)*8);          \
        MFMA(_c1a, _f0, BF0); MFMA(_c1a, _f1, BF1);                            \
        MFMA(_c1a, _f2, BF2); MFMA(_c1a, _f3, BF3);                            \
        _f0 = *(const short8*)(W1f + (((I)*8+4)*64 + lane)*8);                 \
        _f1 = *(const short8*)(W1f + (((I)*8+5)*64 + lane)*8);                 \
        _f2 = *(const short8*)(W1f + (((I)*8+6)*64 + lane)*8);                 \
        _f3 = *(const short8*)(W1f + (((I)*8+7)*64 + lane)*8);                 \
        MFMA(_c1b, _f0, BF0); MFMA(_c1b, _f1, BF1);                            \
        MFMA(_c1b, _f2, BF2); MFMA(_c1b, _f3, BF3);                            \
    }                                                                          \
    short8 _a20, _a21, _a22, _a23;                                             \
    REPACK(_a20, _c1a, 0, 1); REPACK(_a21, _c1a, 2, 3);                        \
    REPACK(_a22, _c1b, 0, 1); REPACK(_a23, _c1b, 2, 3);                        \
    f32x16 _c2a = splat16(BVA), _c2b = splat16(BVB);                           \
    short8 _w20 = *(const short8*)(W2l + (((I)*8 + 0)*64 + lane)*8);           \
    short8 _w24 = *(const short8*)(W2l + (((I)*8 + 4)*64 + lane)*8);           \
    MFMA(_c2a, _a20, _w20); MFMA(_c2b, _a20, _w24);                            \
    short8 _w21 = *(const short8*)(W2l + (((I)*8 + 1)*64 + lane)*8);           \
    short8 _w25 = *(const short8*)(W2l + (((I)*8 + 5)*64 + lane)*8);           \
    MFMA(_c2a, _a21, _w21); MFMA(_c2b, _a21, _w25);                            \
    short8 _w22 = *(const short8*)(W2l + (((I)*8 + 2)*64 + lane)*8);           \
    short8 _w26 = *(const short8*)(W2l + (((I)*8 + 6)*64 + lane)*8);           \
    MFMA(_c2a, _a22, _w22); MFMA(_c2b, _a22, _w26);                            \
    short8 _w23 = *(const short8*)(W2l + (((I)*8 + 3)*64 + lane)*8);           \
    short8 _w27 = *(const short8*)(W2l + (((I)*8 + 7)*64 + lane)*8);           \
    MFMA(_c2a, _a23, _w23); MFMA(_c2b, _a23, _w27);                            \
    EPI_QD(_c2a, _c2b, I, ET, 0); EPI_QD(_c2a, _c2b, I, ET, 1);                \
    EPI_QD(_c2a, _c2b, I, ET, 2); EPI_QD(_c2a, _c2b, I, ET, 3); } while (0)

// ---------------------------------------------------------------------------
// Single fused kernel: one wg per (b, receiver r); 256 threads = 4 waves.
// All weight accesses coalesced or LDS; no strided global gathers (R5 fix).
// ---------------------------------------------------------------------------
__global__ __launch_bounds__(256) void fused_kernel(
    const float* __restrict__ x,        // [B][N][64]
    const float* __restrict__ rel_type, // [B][E][2]
    const float* __restrict__ W1,       // [2][128][64]
    const float* __restrict__ b1,       // [2][64]
    const float* __restrict__ W2,       // [2][64][64]
    const float* __restrict__ b2,       // [2][64]
    const float* __restrict__ Wo1,      // [128][64]
    const float* __restrict__ bo1,      // [64]
    const float* __restrict__ Wo2,      // [64][64]
    const float* __restrict__ bo2,      // [64]
    float* __restrict__ out)
{
    const int b    = blockIdx.x >> 8;
    const int r    = blockIdx.x & 255;
    const int t    = threadIdx.x;
    const int lane = t & 63;
    const int w    = t >> 6;
    const int l31  = lane & 31;
    const int lh   = lane >> 5;

    __shared__ __align__(16) short W1f[8192];      // 16 KiB A1 fragments (sender half)
    __shared__ __align__(16) short W2l[8192];      // 16 KiB B2 fragments
    __shared__ __align__(16) float rt2[2][256];    // 2 KiB
    __shared__ __align__(16) float qrow[2][64];
    __shared__ __align__(16) float red[4][64];
    __shared__ __align__(16) float xl[64];
    __shared__ __align__(16) float aggl[64];
    __shared__ __align__(16) float predl[64];

    const float* xb = x + (size_t)b * (NB * 64);

    // ---- phase A: rt + xl staging, B1 gathers, W1->LDS fragment staging ----
    if (t < 255) {
        const float* p = rel_type + ((size_t)b * NE + (size_t)r * 255 + t) * 2;
        rt2[0][t] = p[0];
        rt2[1][t] = p[1];
    } else {
        rt2[0][255] = 0.f; rt2[1][255] = 0.f;      // pad edge contributes 0
    }
    if (t >= 192) xl[t - 192] = xb[r * 64 + (t - 192)];

    const int kap0 = 64 * w + l31;
    const int kap1 = kap0 + 32;
    int s0 = (kap0 < r) ? kap0 : kap0 + 1; if (s0 > 255) s0 = 255;  // pad row
    int s1 = (kap1 < r) ? kap1 : kap1 + 1; if (s1 > 255) s1 = 255;
    const float* rowA = xb + s0 * 64;
    const float* rowB = xb + s1 * 64;

    short8 B1A0, B1A1, B1A2, B1A3, B1B0, B1B1, B1B2, B1B3;
    MK_B1(B1A0, rowA, 0); MK_B1(B1A1, rowA, 1);
    MK_B1(B1A2, rowA, 2); MK_B1(B1A3, rowA, 3);
    MK_B1(B1B0, rowB, 0); MK_B1(B1B1, rowB, 1);
    MK_B1(B1B2, rowB, 2); MK_B1(B1B3, rowB, 3);

    // W1 sender-half -> bf16 A-fragments in LDS, fully coalesced reads
    // frag(i,ht,k0): W1f[((i*8+ht*4+k0)*64 + lane)*8 + j]
    //             = bf16(W1[i][16*k0 + 8*(lane>>5) + j][l31 + 32*ht])
    #pragma unroll
    for (int i = 0; i < 2; ++i)
        #pragma unroll
        for (int q = 0; q < 16; ++q) {
            const int e = q * 256 + t;
            const int f = e >> 6;                 // 0..63 (sender rows)
            const int h = e & 63;
            const float v = W1[i * 8192 + f * 64 + h];
            const int k0 = f >> 4;
            const int lw = ((f >> 3) & 1) * 32 + (h & 31);
            const int j  = f & 7;
            const int ht = h >> 5;
            W1f[((i * 8 + ht * 4 + k0) * 64 + lw) * 8 + j] = f2bf(v);
        }

    const float bv00 = b2[l31],      bv01 = b2[32 + l31];
    const float bv10 = b2[64 + l31], bv11 = b2[96 + l31];

    __syncthreads();   // xl + W1f ready

    // ---- phase B: q-row (waves 0-1) | W2 fragment staging (waves 2-3) ----
    if (t < 128) {
        const int i = t >> 6, h = t & 63;
        float acc = b1[i * 64 + h];
        const float* w1r = W1 + i * 8192 + 4096;   // receiver rows 64..127
        #pragma unroll 16
        for (int f = 0; f < 64; ++f) acc = fmaf(xl[f], w1r[f * 64 + h], acc);
        qrow[i][h] = acc;
    } else {
        const int i  = (t >> 6) - 2;
        const int ln = t & 63;
        #pragma unroll
        for (int c = 0; c < 8; ++c) {              // c = nh*4 + k0
            const int nh = c >> 2, k0 = c & 3;
            short8 v;
            #pragma unroll
            for (int j = 0; j < 8; ++j) {
                const int k = 16 * k0 + 8 * (ln >> 5) + j;
                const int n = (ln & 31) + 32 * nh;
                v[j] = f2bf(W2[(i * 64 + k) * 64 + n]);
            }
            *(short8*)(W2l + ((i * 8 + c) * 64 + ln) * 8) = v;
        }
    }
    __syncthreads();

    float psum0 = 0.f, psum1 = 0.f;   // per-lane agg partials, h = l31 / l31+32

    TILE(0, 0, B1A0, B1A1, B1A2, B1A3, bv00, bv01);
    TILE(0, 1, B1B0, B1B1, B1B2, B1B3, bv00, bv01);
    TILE(1, 0, B1A0, B1A1, B1A2, B1A3, bv10, bv11);
    TILE(1, 1, B1B0, B1B1, B1B2, B1B3, bv10, bv11);

    // ---- reduce: lane-halves, then waves ----
    psum0 += __shfl_xor(psum0, 32, 64);
    psum1 += __shfl_xor(psum1, 32, 64);
    if (lh == 0) {
        red[w][l31]      = psum0;
        red[w][l31 + 32] = psum1;
    }
    __syncthreads();
    if (t < 64) aggl[t] = red[0][t] + red[1][t] + red[2][t] + red[3][t];
    __syncthreads();

    // ---- output MLP layer 1: aug(128) @ Wo1(128x64) ----
    {
        const float* src = (w < 2) ? (xl + w * 32) : (aggl + (w - 2) * 32);
        const float* Wp  = Wo1 + (w * 32) * 64 + lane;
        float s = 0.f;
        #pragma unroll
        for (int jj = 0; jj < 32; ++jj) s = fmaf(src[jj], Wp[jj * 64], s);
        red[w][lane] = s;
    }
    __syncthreads();
    if (t < 64)
        predl[t] = fmaxf(red[0][t] + red[1][t] + red[2][t] + red[3][t] + bo1[t], 0.f);
    __syncthreads();

    // ---- output MLP layer 2 + residual ----
    {
        const float* Wp = Wo2 + (w * 16) * 64 + lane;
        float s = 0.f;
        #pragma unroll
        for (int jj = 0; jj < 16; ++jj) s = fmaf(predl[w * 16 + jj], Wp[jj * 64], s);
        red[w][lane] = s;
    }
    __syncthreads();
    if (t < 64)
        out[((size_t)b * NB + r) * 64 + t] =
            xl[t] + fmaxf(red[0][t] + red[1][t] + red[2][t] + red[3][t] + bo2[t], 0.f);
}

// ---------------------------------------------------------------------------
extern "C" void kernel_launch(void* const* d_in, const int* in_sizes, int n_in,
                              void* d_out, int out_size, void* d_ws, size_t ws_size,
                              hipStream_t stream) {
    (void)in_sizes; (void)n_in; (void)out_size; (void)d_ws; (void)ws_size;

    const float* x    = (const float*)d_in[0];
    const float* rt   = (const float*)d_in[1];
    // d_in[2] = rel_rec, d_in[3] = rel_send: dense all-pairs one-hot, unused
    const float* W1   = (const float*)d_in[4];
    const float* b1   = (const float*)d_in[5];
    const float* W2   = (const float*)d_in[6];
    const float* b2   = (const float*)d_in[7];
    const float* Wo1  = (const float*)d_in[8];
    const float* bo1  = (const float*)d_in[9];
    const float* Wo2  = (const float*)d_in[10];
    const float* bo2  = (const float*)d_in[11];
    float* out = (float*)d_out;

    fused_kernel<<<BATCH * NB, 256, 0, stream>>>(x, rt, W1, b1, W2, b2,
                                                 Wo1, bo1, Wo2, bo2, out);
}

// Round 7
// 25.093 us; speedup vs baseline: 4.6218x; 1.2241x over previous
//
#include <hip/hip_runtime.h>
#include <hip/hip_bf16.h>

#define BATCH 4
#define NB    256
#define NE    (NB*(NB-1))   // 65280

typedef short    short8 __attribute__((ext_vector_type(8)));
typedef float    f32x16 __attribute__((ext_vector_type(16)));

static __device__ __forceinline__ short f2bf(float x) {
    return __builtin_bit_cast(short, __float2bfloat16(x));   // RNE
}
static __device__ __forceinline__ float bf2f(short s) {
    unsigned u = ((unsigned)(unsigned short)s) << 16;
    return __builtin_bit_cast(float, u);
}
static __device__ __forceinline__ f32x16 splat16(float v) {
    f32x16 r;
    #pragma unroll
    for (int e = 0; e < 16; ++e) r[e] = v;
    return r;
}

#define MFMA(C, A, B) C = __builtin_amdgcn_mfma_f32_32x32x16_bf16(A, B, C, 0, 0, 0)

// A-frag from row-major [row][k] f32: lane row = l31(+tile), k = 16*K0+8*lh+j
#define MK_B1(dst, ROW, K0) do {                                               \
    float4 _u0 = *(const float4*)((ROW) + 16*(K0) + 8*lh);                     \
    float4 _u1 = *(const float4*)((ROW) + 16*(K0) + 8*lh + 4);                 \
    short8 _v = { f2bf(_u0.x), f2bf(_u0.y), f2bf(_u0.z), f2bf(_u0.w),          \
                  f2bf(_u1.x), f2bf(_u1.y), f2bf(_u1.z), f2bf(_u1.w) };        \
    (dst) = _v; } while (0)

// B-frag from [k][col] f32 (stride 64): lane col = l31+32*HT, k = 16*K0+8*lh+j
#define MK_A1(dst, Wp, K0, HT) do {                                            \
    const float* _p = (Wp) + (16*(K0) + 8*lh) * 64 + (l31 + 32*(HT));          \
    short8 _v;                                                                 \
    _v[0]=f2bf(_p[0]);   _v[1]=f2bf(_p[64]);  _v[2]=f2bf(_p[128]);             \
    _v[3]=f2bf(_p[192]); _v[4]=f2bf(_p[256]); _v[5]=f2bf(_p[320]);             \
    _v[6]=f2bf(_p[384]); _v[7]=f2bf(_p[448]);                                  \
    (dst) = _v; } while (0)

// ---------------------------------------------------------------------------
// prep (9 wgs): blk<8 = (i,b) node GEMMs via MFMA -> Pbf (frag layout) + Qg;
//               blk==8 = W2 -> bf16 B-fragments (read-coalesced decode).
//   Pbf [i*4+b][hb][n][8] bf16 : P = x·W1[:64]
//   Qg  [i*4+b][n][64]   f32   : x·W1[64:] + b1
//   W2f [2][2][4][64][8] bf16
// ---------------------------------------------------------------------------
__global__ __launch_bounds__(256) void prep_kernel(
    const float* __restrict__ x,   // [B][N][64]
    const float* __restrict__ W1,  // [2][128][64]
    const float* __restrict__ b1,  // [2][64]
    const float* __restrict__ W2,  // [2][64][64]
    short* __restrict__ Pbf,
    float* __restrict__ Qg,
    short* __restrict__ W2f)
{
    const int t    = threadIdx.x;
    const int lane = t & 63;
    const int w    = t >> 6;
    const int l31  = lane & 31;
    const int lh   = lane >> 5;
    const int blk  = blockIdx.x;

    if (blk < 8) {
        const int i   = blk >> 2;
        const int b   = blk & 3;
        const int ibb = i * 4 + b;
        const float* xb  = x + (size_t)b * NB * 64;
        const float* w1s = W1 + i * 8192;          // sender rows 0..63
        const float* w1r = w1s + 4096;             // receiver rows 64..127
        const float  b1v0 = b1[i * 64 + l31];
        const float  b1v1 = b1[i * 64 + 32 + l31];

        const float* rowA = xb + (64 * w + l31) * 64;
        const float* rowB = xb + (64 * w + 32 + l31) * 64;
        short8 AR00, AR01, AR02, AR03, AR10, AR11, AR12, AR13;
        MK_B1(AR00, rowA, 0); MK_B1(AR01, rowA, 1);
        MK_B1(AR02, rowA, 2); MK_B1(AR03, rowA, 3);
        MK_B1(AR10, rowB, 0); MK_B1(AR11, rowB, 1);
        MK_B1(AR12, rowB, 2); MK_B1(AR13, rowB, 3);

#define WR_P(C, RT, CT) do {                                                   \
    _Pragma("unroll")                                                          \
    for (int rg = 0; rg < 16; ++rg) {                                          \
        const int nn = 64*w + 32*(RT) + (rg & 3) + 8*(rg >> 2) + 4*lh;         \
        const int hh = l31 + 32*(CT);                                          \
        Pbf[(size_t)ibb*16384 + (hh>>3)*2048 + nn*8 + (hh&7)] = f2bf((C)[rg]); \
    } } while (0)
#define WR_Q0(C, RT, CT) do {                                                  \
    _Pragma("unroll")                                                          \
    for (int rg = 0; rg < 16; ++rg) {                                          \
        const int nn = 64*w + 32*(RT) + (rg & 3) + 8*(rg >> 2) + 4*lh;         \
        Qg[(size_t)ibb*16384 + nn*64 + l31] = (C)[rg] + b1v0;                  \
    } } while (0)
#define WR_Q1(C, RT, CT) do {                                                  \
    _Pragma("unroll")                                                          \
    for (int rg = 0; rg < 16; ++rg) {                                          \
        const int nn = 64*w + 32*(RT) + (rg & 3) + 8*(rg >> 2) + 4*lh;         \
        Qg[(size_t)ibb*16384 + nn*64 + 32 + l31] = (C)[rg] + b1v1;             \
    } } while (0)
#define PREP_GEMM(WSRC, CT, WRM) do {                                          \
    short8 _B0, _B1, _B2, _B3;                                                 \
    MK_A1(_B0, WSRC, 0, CT); MK_A1(_B1, WSRC, 1, CT);                          \
    MK_A1(_B2, WSRC, 2, CT); MK_A1(_B3, WSRC, 3, CT);                          \
    f32x16 _c0 = splat16(0.f), _c1 = splat16(0.f);                             \
    MFMA(_c0, AR00, _B0); MFMA(_c0, AR01, _B1);                                \
    MFMA(_c0, AR02, _B2); MFMA(_c0, AR03, _B3);                                \
    MFMA(_c1, AR10, _B0); MFMA(_c1, AR11, _B1);                                \
    MFMA(_c1, AR12, _B2); MFMA(_c1, AR13, _B3);                                \
    WRM(_c0, 0, CT); WRM(_c1, 1, CT); } while (0)

        PREP_GEMM(w1s, 0, WR_P);
        PREP_GEMM(w1s, 1, WR_P);
        PREP_GEMM(w1r, 0, WR_Q0);
        PREP_GEMM(w1r, 1, WR_Q1);
    } else {
        // W2 -> fragments, source-coalesced reads, small scatter writes
        #pragma unroll
        for (int q = 0; q < 32; ++q) {
            const int e = q * 256 + t;             // == i*4096 + k*64 + n
            const int i = e >> 12, k = (e >> 6) & 63, n = e & 63;
            const float v = W2[e];
            const int k0 = k >> 4, j = k & 7, hm = (k >> 3) & 1;
            const int nt = n >> 5;
            W2f[(((i*2 + nt)*4 + k0)*64 + hm*32 + (n & 31))*8 + j] = f2bf(v);
        }
    }
}

// ---------------------------------------------------------------------------
// main: one wg per (b, receiver r); 256 threads = 4 waves. Edge work only:
// gather Pbf (coalesced b128) -> relu(P[s]+Q[r]) -> GEMM2 -> weighted reduce
// -> fused output MLP. Fully scalarized (no local arrays).
// ---------------------------------------------------------------------------

// A2 frag: relu(bf2f(P) + qrow) -> bf16, k-elems h = 16*K0+8*lh+j
#define MK_A2(dst, PV, I, K0) do {                                             \
    float4 _q0 = *(const float4*)(&qrow[I][16*(K0) + 8*lh]);                   \
    float4 _q1 = *(const float4*)(&qrow[I][16*(K0) + 8*lh + 4]);               \
    short8 _v;                                                                 \
    _v[0] = f2bf(fmaxf(bf2f((PV)[0]) + _q0.x, 0.f));                           \
    _v[1] = f2bf(fmaxf(bf2f((PV)[1]) + _q0.y, 0.f));                           \
    _v[2] = f2bf(fmaxf(bf2f((PV)[2]) + _q0.z, 0.f));                           \
    _v[3] = f2bf(fmaxf(bf2f((PV)[3]) + _q0.w, 0.f));                           \
    _v[4] = f2bf(fmaxf(bf2f((PV)[4]) + _q1.x, 0.f));                           \
    _v[5] = f2bf(fmaxf(bf2f((PV)[5]) + _q1.y, 0.f));                           \
    _v[6] = f2bf(fmaxf(bf2f((PV)[6]) + _q1.z, 0.f));                           \
    _v[7] = f2bf(fmaxf(bf2f((PV)[7]) + _q1.w, 0.f));                           \
    (dst) = _v; } while (0)

#define EPI_QD(C2A, C2B, I, ET, QD) do {                                       \
    float4 _rq = *(const float4*)(&rt2[I][64*w + 32*(ET) + 8*(QD) + 4*lh]);    \
    psum0 += fmaxf((C2A)[4*(QD)],   0.f) * _rq.x;                              \
    psum0 += fmaxf((C2A)[4*(QD)+1], 0.f) * _rq.y;                              \
    psum0 += fmaxf((C2A)[4*(QD)+2], 0.f) * _rq.z;                              \
    psum0 += fmaxf((C2A)[4*(QD)+3], 0.f) * _rq.w;                              \
    psum1 += fmaxf((C2B)[4*(QD)],   0.f) * _rq.x;                              \
    psum1 += fmaxf((C2B)[4*(QD)+1], 0.f) * _rq.y;                              \
    psum1 += fmaxf((C2B)[4*(QD)+2], 0.f) * _rq.z;                              \
    psum1 += fmaxf((C2B)[4*(QD)+3], 0.f) * _rq.w; } while (0)

#define TILE2(I, ET, PA, PB, PC, PD, BVA, BVB) do {                            \
    short8 _a0, _a1, _a2, _a3;                                                 \
    MK_A2(_a0, PA, I, 0); MK_A2(_a1, PB, I, 1);                                \
    MK_A2(_a2, PC, I, 2); MK_A2(_a3, PD, I, 3);                                \
    f32x16 _c2a = splat16(BVA), _c2b = splat16(BVB);                           \
    short8 _w0 = *(const short8*)(W2l + (((I)*8 + 0)*64 + lane)*8);            \
    short8 _w4 = *(const short8*)(W2l + (((I)*8 + 4)*64 + lane)*8);            \
    MFMA(_c2a, _a0, _w0); MFMA(_c2b, _a0, _w4);                                \
    _w0 = *(const short8*)(W2l + (((I)*8 + 1)*64 + lane)*8);                   \
    _w4 = *(const short8*)(W2l + (((I)*8 + 5)*64 + lane)*8);                   \
    MFMA(_c2a, _a1, _w0); MFMA(_c2b, _a1, _w4);                                \
    _w0 = *(const short8*)(W2l + (((I)*8 + 2)*64 + lane)*8);                   \
    _w4 = *(const short8*)(W2l + (((I)*8 + 6)*64 + lane)*8);                   \
    MFMA(_c2a, _a2, _w0); MFMA(_c2b, _a2, _w4);                                \
    _w0 = *(const short8*)(W2l + (((I)*8 + 3)*64 + lane)*8);                   \
    _w4 = *(const short8*)(W2l + (((I)*8 + 7)*64 + lane)*8);                   \
    MFMA(_c2a, _a3, _w0); MFMA(_c2b, _a3, _w4);                                \
    EPI_QD(_c2a, _c2b, I, ET, 0); EPI_QD(_c2a, _c2b, I, ET, 1);                \
    EPI_QD(_c2a, _c2b, I, ET, 2); EPI_QD(_c2a, _c2b, I, ET, 3); } while (0)

#define LD_P(I, K0, S) \
    (*(const short8*)(PbfG + ((size_t)((I)*4+b)*8 + 2*(K0)+lh)*2048 + (size_t)(S)*8))

__global__ __launch_bounds__(256) void main_kernel(
    const float* __restrict__ x,
    const float* __restrict__ rel_type, // [B][E][2]
    const float* __restrict__ b2,       // [2][64]
    const float* __restrict__ Wo1,      // [128][64]
    const float* __restrict__ bo1,
    const float* __restrict__ Wo2,      // [64][64]
    const float* __restrict__ bo2,
    const short* __restrict__ PbfG,
    const float* __restrict__ Qg,
    const short* __restrict__ W2fG,
    float* __restrict__ out)
{
    const int b    = blockIdx.x >> 8;
    const int r    = blockIdx.x & 255;
    const int t    = threadIdx.x;
    const int lane = t & 63;
    const int w    = t >> 6;
    const int l31  = lane & 31;
    const int lh   = lane >> 5;

    __shared__ __align__(16) short W2l[8192];      // 16 KiB
    __shared__ __align__(16) float rt2[2][256];
    __shared__ __align__(16) float qrow[2][64];
    __shared__ __align__(16) float red[4][64];
    __shared__ __align__(16) float xl[64];
    __shared__ __align__(16) float aggl[64];
    __shared__ __align__(16) float predl[64];

    const float* xb = x + (size_t)b * NB * 64;

    // ---- staging ----
    if (t < 255) {
        const float* p = rel_type + ((size_t)b * NE + (size_t)r * 255 + t) * 2;
        rt2[0][t] = p[0];
        rt2[1][t] = p[1];
    } else {
        rt2[0][255] = 0.f; rt2[1][255] = 0.f;      // pad edge contributes 0
    }
    #pragma unroll
    for (int q = 0; q < 4; ++q) {                  // W2 frags -> LDS (b128 copy)
        const int e = (q * 256 + t) * 8;
        *(short8*)(W2l + e) = *(const short8*)(W2fG + e);
    }
    if (t < 128) {
        const int i = t >> 6, h = t & 63;
        qrow[i][h] = Qg[(size_t)(i * 4 + b) * 16384 + r * 64 + h];
    }
    if (t >= 192) xl[t - 192] = xb[r * 64 + (t - 192)];

    // edge rows for this wave's two M-tiles
    const int kap0 = 64 * w + l31;
    const int kap1 = kap0 + 32;
    int s0 = (kap0 < r) ? kap0 : kap0 + 1; if (s0 > 255) s0 = 255;  // pad row
    int s1 = (kap1 < r) ? kap1 : kap1 + 1; if (s1 > 255) s1 = 255;

    // Pbf gathers (coalesced 16B/lane), issued before the barrier
    short8 P000 = LD_P(0,0,s0), P001 = LD_P(0,1,s0), P002 = LD_P(0,2,s0), P003 = LD_P(0,3,s0);
    short8 P010 = LD_P(0,0,s1), P011 = LD_P(0,1,s1), P012 = LD_P(0,2,s1), P013 = LD_P(0,3,s1);
    short8 P100 = LD_P(1,0,s0), P101 = LD_P(1,1,s0), P102 = LD_P(1,2,s0), P103 = LD_P(1,3,s0);
    short8 P110 = LD_P(1,0,s1), P111 = LD_P(1,1,s1), P112 = LD_P(1,2,s1), P113 = LD_P(1,3,s1);

    const float bv00 = b2[l31],      bv01 = b2[32 + l31];
    const float bv10 = b2[64 + l31], bv11 = b2[96 + l31];

    __syncthreads();

    float psum0 = 0.f, psum1 = 0.f;   // per-lane agg partials, h = l31 / l31+32

    TILE2(0, 0, P000, P001, P002, P003, bv00, bv01);
    TILE2(0, 1, P010, P011, P012, P013, bv00, bv01);
    TILE2(1, 0, P100, P101, P102, P103, bv10, bv11);
    TILE2(1, 1, P110, P111, P112, P113, bv10, bv11);

    // ---- reduce: lane-halves, then waves ----
    psum0 += __shfl_xor(psum0, 32, 64);
    psum1 += __shfl_xor(psum1, 32, 64);
    if (lh == 0) {
        red[w][l31]      = psum0;
        red[w][l31 + 32] = psum1;
    }
    __syncthreads();
    if (t < 64) aggl[t] = red[0][t] + red[1][t] + red[2][t] + red[3][t];
    __syncthreads();

    // ---- output MLP layer 1: aug(128) @ Wo1(128x64) ----
    {
        const float* src = (w < 2) ? (xl + w * 32) : (aggl + (w - 2) * 32);
        const float* Wp  = Wo1 + (w * 32) * 64 + lane;
        float s = 0.f;
        #pragma unroll
        for (int jj = 0; jj < 32; ++jj) s = fmaf(src[jj], Wp[jj * 64], s);
        red[w][lane] = s;
    }
    __syncthreads();
    if (t < 64)
        predl[t] = fmaxf(red[0][t] + red[1][t] + red[2][t] + red[3][t] + bo1[t], 0.f);
    __syncthreads();

    // ---- output MLP layer 2 + residual ----
    {
        const float* Wp = Wo2 + (w * 16) * 64 + lane;
        float s = 0.f;
        #pragma unroll
        for (int jj = 0; jj < 16; ++jj) s = fmaf(predl[w * 16 + jj], Wp[jj * 64], s);
        red[w][lane] = s;
    }
    __syncthreads();
    if (t < 64)
        out[((size_t)b * NB + r) * 64 + t] =
            xl[t] + fmaxf(red[0][t] + red[1][t] + red[2][t] + red[3][t] + bo2[t], 0.f);
}

// ---------------------------------------------------------------------------
extern "C" void kernel_launch(void* const* d_in, const int* in_sizes, int n_in,
                              void* d_out, int out_size, void* d_ws, size_t ws_size,
                              hipStream_t stream) {
    (void)in_sizes; (void)n_in; (void)out_size; (void)ws_size;

    const float* x    = (const float*)d_in[0];
    const float* rt   = (const float*)d_in[1];
    // d_in[2] = rel_rec, d_in[3] = rel_send: dense all-pairs one-hot, unused
    const float* W1   = (const float*)d_in[4];
    const float* b1   = (const float*)d_in[5];
    const float* W2   = (const float*)d_in[6];
    const float* b2   = (const float*)d_in[7];
    const float* Wo1  = (const float*)d_in[8];
    const float* bo1  = (const float*)d_in[9];
    const float* Wo2  = (const float*)d_in[10];
    const float* bo2  = (const float*)d_in[11];
    float* out = (float*)d_out;

    char* ws = (char*)d_ws;
    short* Pbf = (short*)ws;                 // 8*16384*2B  = 256 KiB
    float* Qg  = (float*)(ws + 262144);      // 8*16384*4B  = 512 KiB
    short* W2f = (short*)(ws + 786432);      // 16 KiB

    prep_kernel<<<9, 256, 0, stream>>>(x, W1, b1, W2, Pbf, Qg, W2f);
    main_kernel<<<BATCH * NB, 256, 0, stream>>>(x, rt, b2, Wo1, bo1, Wo2, bo2,
                                                Pbf, Qg, W2f, out);
}